// Round 6
// baseline (357.666 us; speedup 1.0000x reference)
//
#include <hip/hip_runtime.h>
#include <hip/hip_bf16.h>

// MambaLM: B=2,K=4,T=1024,V=1024, d_model=512, d_inner=1024, N=16, dt_rank=32, L=2
// R6: 17 dispatches (from 21): mega-merged cvt/transpose/embed, dt_proj fused into
// scans (f32 math, dtb eliminated); 128x64 GEMM tiles -> 2-4 blocks/CU for
// in_proj + single-dispatch head (N=4096).

#define B_SZ 2
#define K_CB 4
#define T_SZ 1024
#define V_SZ 1024
#define DM 512
#define DI 1024
#define NS 16
#define DTR 32
#define NCHUNK 64
#define TCHUNK 16

typedef unsigned short u16;
typedef long long ll;
using short8 = __attribute__((ext_vector_type(8))) short;
using f32x4  = __attribute__((ext_vector_type(4))) float;

__device__ __forceinline__ float bf2f(u16 u) {
    union { unsigned int i; float f; } v; v.i = ((unsigned int)u) << 16; return v.f;
}
__device__ __forceinline__ u16 f2bf(float f) {
    union { float f; unsigned int i; } v; v.f = f;
    unsigned int x = v.i;
    return (u16)((x + 0x7fffu + ((x >> 16) & 1u)) >> 16);
}
__device__ __forceinline__ float siluf(float x) { return x / (1.f + __expf(-x)); }
__device__ __forceinline__ float softplusf(float x) { return (x > 20.f) ? x : log1pf(__expf(x)); }

__device__ __forceinline__ void gld16(const void* g, void* l) {
    __builtin_amdgcn_global_load_lds(
        (const __attribute__((address_space(1))) unsigned int*)g,
        (__attribute__((address_space(3))) unsigned int*)l, 16, 0, 0);
}

// ---------------- mega setup kernel: weight cvt (3200 blk) + head transpose (512 blk)
//                  + embed+rmsnorm (2048 blk) ----------------
__global__ __launch_bounds__(256) void mega0_k(const float* __restrict__ in_w,
                                               const float* __restrict__ xp_w,
                                               const float* __restrict__ out_w,
                                               u16* __restrict__ w_in, u16* __restrict__ w_xp,
                                               u16* __restrict__ w_out,
                                               const float* __restrict__ head_w,
                                               u16* __restrict__ w_hd,
                                               const int* __restrict__ codes,
                                               const float* __restrict__ ew,
                                               const float* __restrict__ nw,
                                               float* __restrict__ x,
                                               u16* __restrict__ xn) {
    __shared__ float tile[64][65];
    int bid = blockIdx.x;
    int tid = threadIdx.x;
    if (bid < 3200) {
        // flat f32->bf16: in_w (2097152) | xp_w (131072) | out_w (1048576)
        int i = (bid * 256 + tid) << 2;
        const float* s; u16* d;
        if (i < 2097152) { s = in_w + i; d = w_in + i; }
        else {
            i -= 2097152;
            if (i < 131072) { s = xp_w + i; d = w_xp + i; }
            else { i -= 131072; s = out_w + i; d = w_out + i; }
        }
        float4 v = *(const float4*)s;
        ushort4 o; o.x = f2bf(v.x); o.y = f2bf(v.y); o.z = f2bf(v.z); o.w = f2bf(v.w);
        *(ushort4*)d = o;
    } else if (bid < 3712) {
        // head transpose: w[4][512][1024] f32 -> wt[4][1024][512] bf16
        int idx = bid - 3200;
        int z = idx >> 7, rest = idx & 127;
        int d0 = (rest >> 4) << 6, v0 = (rest & 15) << 6;
        int col = tid & 63, rbase = tid >> 6;
#pragma unroll
        for (int i = 0; i < 16; i++) {
            int row = (i << 2) + rbase;
            tile[row][col] = head_w[(ll)z * (DM * V_SZ) + (ll)(d0 + row) * V_SZ + v0 + col];
        }
        __syncthreads();
#pragma unroll
        for (int i = 0; i < 16; i++) {
            int vrow = (i << 2) + rbase;
            w_hd[(ll)z * (V_SZ * DM) + (ll)(v0 + vrow) * DM + d0 + col] = f2bf(tile[col][vrow]);
        }
    } else {
        // embedding + rmsnorm (layer-0 input)
        int row = bid - 3712;  // b*1024 + t
        int b = row >> 10, t = row & 1023;
        float a0 = 0.f, a1 = 0.f;
#pragma unroll
        for (int k = 0; k < K_CB; k++) {
            int c = codes[b * (K_CB * T_SZ) + k * T_SZ + t];
            a0 += ew[((ll)k * V_SZ + c) * DM + tid];
            a1 += ew[((ll)k * V_SZ + c) * DM + tid + 256];
        }
        x[(ll)row * DM + tid]       = a0;
        x[(ll)row * DM + tid + 256] = a1;
        float ss = a0 * a0 + a1 * a1;
#pragma unroll
        for (int off = 32; off > 0; off >>= 1) ss += __shfl_down(ss, off, 64);
        float* red = &tile[0][0];
        if ((tid & 63) == 0) red[tid >> 6] = ss;
        __syncthreads();
        float tot = red[0] + red[1] + red[2] + red[3];
        float scale = rsqrtf(tot * (1.0f / DM) + 1e-6f);
        xn[(ll)row * DM + tid]       = f2bf(a0 * scale * nw[tid]);
        xn[(ll)row * DM + tid + 256] = f2bf(a1 * scale * nw[tid + 256]);
    }
}

// ---------------- rmsnorm (layer 1): f32 in -> bf16 out ----------------
__global__ __launch_bounds__(256) void rmsnorm_k(const float* __restrict__ x,
                                                 const float* __restrict__ w,
                                                 u16* __restrict__ xn) {
    ll row = blockIdx.x;
    const float* xr = x + row * DM;
    int tid = threadIdx.x;
    float v0 = xr[tid], v1 = xr[tid + 256];
    float ss = v0 * v0 + v1 * v1;
#pragma unroll
    for (int off = 32; off > 0; off >>= 1) ss += __shfl_down(ss, off, 64);
    __shared__ float red[4];
    if ((tid & 63) == 0) red[tid >> 6] = ss;
    __syncthreads();
    float tot = red[0] + red[1] + red[2] + red[3];
    float scale = rsqrtf(tot * (1.0f / DM) + 1e-6f);
    xn[row * DM + tid]       = f2bf(v0 * scale * w[tid]);
    xn[row * DM + tid + 256] = f2bf(v1 * scale * w[tid + 256]);
}

// ---------------- 128m x 64n MFMA GEMM, global_load_lds staging ----------------
// C[M,N] = A[M,K](bf16) * W[N,K](bf16)^T.  4 waves 2x2 -> each wave 64m x 32n.
// EP0: bf16 store Cb (in_proj).  EP4: head f32 scatter (N=4096 = [z=n>>10][v=n&1023]).
template <int EP>
__global__ __launch_bounds__(256) void mgemm3_k(const u16* __restrict__ A, int lda,
                                                const u16* __restrict__ W,
                                                float* __restrict__ C,
                                                u16* __restrict__ Cb, int ldcb, int K) {
    __shared__ u16 As[4096];  // [128][32]
    __shared__ u16 Bs[2048];  // [64][32]
    int tid = threadIdx.x;
    int wave = tid >> 6, lane = tid & 63;
    int q = lane >> 4, r = lane & 15;
    int m0 = blockIdx.y << 7, n0 = blockIdx.x << 6;
    int wm = (wave >> 1) << 6, wn = (wave & 1) << 5;
    int sA0 = (wave << 7) + lane, sA1 = sA0 + 64;
    int sB = (wave << 6) + lane;
    f32x4 acc[4][2];
#pragma unroll
    for (int i = 0; i < 4; i++)
#pragma unroll
        for (int j = 0; j < 2; j++) acc[i][j] = (f32x4){0.f, 0.f, 0.f, 0.f};

    for (int k0 = 0; k0 < K; k0 += 32) {
        gld16(A + (ll)(m0 + (sA0 >> 2)) * lda + k0 + ((sA0 & 3) << 3), &As[wave << 10]);
        gld16(A + (ll)(m0 + (sA1 >> 2)) * lda + k0 + ((sA1 & 3) << 3), &As[(wave << 10) + 512]);
        gld16(W + (ll)(n0 + (sB  >> 2)) * K   + k0 + ((sB  & 3) << 3), &Bs[wave << 9]);
        __syncthreads();
        short8 af[4], bfr[2];
#pragma unroll
        for (int i = 0; i < 4; i++) af[i]  = *(const short8*)&As[((wm + (i << 4) + r) << 5) + (q << 3)];
#pragma unroll
        for (int j = 0; j < 2; j++) bfr[j] = *(const short8*)&Bs[((wn + (j << 4) + r) << 5) + (q << 3)];
#pragma unroll
        for (int i = 0; i < 4; i++)
#pragma unroll
            for (int j = 0; j < 2; j++)
                acc[i][j] = __builtin_amdgcn_mfma_f32_16x16x32_bf16(af[i], bfr[j], acc[i][j], 0, 0, 0);
        __syncthreads();
    }

#pragma unroll
    for (int i = 0; i < 4; i++)
#pragma unroll
        for (int j = 0; j < 2; j++)
#pragma unroll
            for (int g = 0; g < 4; g++) {
                int m = m0 + wm + (i << 4) + (q << 2) + g;
                int n = n0 + wn + (j << 4) + r;
                float v = acc[i][j][g];
                if (EP == 0) {
                    Cb[(ll)m * ldcb + n] = f2bf(v);
                } else {
                    int z = n >> 10, vv = n & 1023;
                    int b = m >> 10, t = m & 1023;
                    C[((ll)(b * K_CB + z) * T_SZ + t) * V_SZ + vv] = v;
                }
            }
}

// ---------------- 64x64 MFMA GEMM ----------------
// EP1: f32 store (x_proj).  EP3: C += acc, Cb = bf16(C) (out_proj).
template <int EP>
__global__ __launch_bounds__(256) void mgemm_k(const u16* __restrict__ A, int lda,
                                               const u16* __restrict__ W,
                                               float* __restrict__ C, int ldc, int K,
                                               u16* __restrict__ Cb, int ldcb) {
    __shared__ u16 As[64][40];
    __shared__ u16 Bs[64][40];
    int tid = threadIdx.x;
    int m0 = blockIdx.y << 6, n0 = blockIdx.x << 6;
    int lane = tid & 63, wave = tid >> 6;
    int q = lane >> 4, r = lane & 15;
    int wm = (wave >> 1) << 5, wn = (wave & 1) << 5;
    int srow = tid >> 2, sseg = (tid & 3) << 3;
    f32x4 acc[2][2];
#pragma unroll
    for (int i = 0; i < 2; i++)
#pragma unroll
        for (int j = 0; j < 2; j++) acc[i][j] = (f32x4){0.f, 0.f, 0.f, 0.f};

    for (int k0 = 0; k0 < K; k0 += 32) {
        *(uint4*)&As[srow][sseg] = *(const uint4*)&A[(ll)(m0 + srow) * lda + k0 + sseg];
        *(uint4*)&Bs[srow][sseg] = *(const uint4*)&W[(ll)(n0 + srow) * K + k0 + sseg];
        __syncthreads();
        short8 af[2], bfr[2];
#pragma unroll
        for (int i = 0; i < 2; i++) af[i]  = *(const short8*)&As[wm + (i << 4) + r][q << 3];
#pragma unroll
        for (int j = 0; j < 2; j++) bfr[j] = *(const short8*)&Bs[wn + (j << 4) + r][q << 3];
#pragma unroll
        for (int i = 0; i < 2; i++)
#pragma unroll
            for (int j = 0; j < 2; j++)
                acc[i][j] = __builtin_amdgcn_mfma_f32_16x16x32_bf16(af[i], bfr[j], acc[i][j], 0, 0, 0);
        __syncthreads();
    }

#pragma unroll
    for (int i = 0; i < 2; i++)
#pragma unroll
        for (int j = 0; j < 2; j++)
#pragma unroll
            for (int g = 0; g < 4; g++) {
                int m = m0 + wm + (i << 4) + (q << 2) + g;
                int n = n0 + wn + (j << 4) + r;
                float v = acc[i][j][g];
                if (EP == 1) {
                    C[(ll)m * ldc + n] = v;
                } else {
                    float nv = C[(ll)m * ldc + n] + v;
                    C[(ll)m * ldc + n] = nv;
                    Cb[(ll)m * ldcb + n] = f2bf(nv);
                }
            }
}

// ---------------- causal dwconv(4) + bias + silu, ushort4-vectorized ----------------
__global__ __launch_bounds__(256) void conv_k(const u16* __restrict__ xzb,
                                              const float* __restrict__ cw,
                                              const float* __restrict__ cb,
                                              float* __restrict__ xc,
                                              u16* __restrict__ xcb) {
    int row = blockIdx.x;  // b*1024+t
    int b = row >> 10, t = row & 1023;
    int c0 = threadIdx.x << 2;
    float4 a = *(const float4*)&cb[c0];
    float acc[4] = {a.x, a.y, a.z, a.w};
    float4 cwv[4];
#pragma unroll
    for (int e = 0; e < 4; e++) cwv[e] = *(const float4*)&cw[(c0 + e) << 2];
#pragma unroll
    for (int j = 0; j < 4; j++) {
        int tt = t - 3 + j;
        if (tt >= 0) {
            ushort4 v = *(const ushort4*)&xzb[((ll)(b * T_SZ + tt)) * (2 * DI) + c0];
            acc[0] = fmaf(bf2f(v.x), ((const float*)&cwv[0])[j], acc[0]);
            acc[1] = fmaf(bf2f(v.y), ((const float*)&cwv[1])[j], acc[1]);
            acc[2] = fmaf(bf2f(v.z), ((const float*)&cwv[2])[j], acc[2]);
            acc[3] = fmaf(bf2f(v.w), ((const float*)&cwv[3])[j], acc[3]);
        }
    }
    float4 s; ushort4 sb;
    s.x = siluf(acc[0]); s.y = siluf(acc[1]); s.z = siluf(acc[2]); s.w = siluf(acc[3]);
    sb.x = f2bf(s.x); sb.y = f2bf(s.y); sb.z = f2bf(s.z); sb.w = f2bf(s.w);
    *(float4*)&xc[(ll)row * DI + c0] = s;
    *(ushort4*)&xcb[(ll)row * DI + c0] = sb;
}

// ---------------- chunked selective scan (dt computed inline, f32) ----------------
// pass 1: per-chunk (prodA, U). grid = B*NCHUNK*(DI/256) = 512 blocks
__global__ __launch_bounds__(256) void scan1_k(const float* __restrict__ xc,
                                               const float* __restrict__ xdbl,
                                               const float* __restrict__ dtw,
                                               const float* __restrict__ dtb_,
                                               const float* __restrict__ A_log,
                                               float* __restrict__ pA, float* __restrict__ U) {
    int blk = blockIdx.x;
    int dblk = blk & 3;
    int c = (blk >> 2) & (NCHUNK - 1);
    int b = blk >> 8;
    int d = dblk * 256 + threadIdx.x;
    int t0 = c * TCHUNK;
    __shared__ float BC[TCHUNK][64];
    {
        int rr = threadIdx.x >> 4, cc = (threadIdx.x & 15) << 2;
        *(float4*)&BC[rr][cc] = *(const float4*)&xdbl[((ll)(b * T_SZ + t0 + rr)) * 64 + cc];
    }
    float wd[DTR];
#pragma unroll
    for (int k4 = 0; k4 < 8; k4++) {
        float4 w4 = *(const float4*)&dtw[d * DTR + (k4 << 2)];
        wd[(k4 << 2) + 0] = w4.x; wd[(k4 << 2) + 1] = w4.y;
        wd[(k4 << 2) + 2] = w4.z; wd[(k4 << 2) + 3] = w4.w;
    }
    float bias = dtb_[d];
    float Av[NS];
#pragma unroll
    for (int n4 = 0; n4 < 4; n4++) {
        float4 alv = *(const float4*)&A_log[d * NS + (n4 << 2)];
        Av[(n4 << 2) + 0] = -__expf(alv.x); Av[(n4 << 2) + 1] = -__expf(alv.y);
        Av[(n4 << 2) + 2] = -__expf(alv.z); Av[(n4 << 2) + 3] = -__expf(alv.w);
    }
    __syncthreads();
    float p[NS], u[NS];
#pragma unroll
    for (int n = 0; n < NS; n++) { p[n] = 1.f; u[n] = 0.f; }
#pragma unroll
    for (int s = 0; s < TCHUNK; s++) {
        ll ro = (ll)(b * T_SZ + t0 + s);
        float adt = bias;
#pragma unroll
        for (int k = 0; k < DTR; k++) adt = fmaf(BC[s][k], wd[k], adt);
        float dtv = softplusf(adt);
        float xv = xc[ro * DI + d];
        float dx = dtv * xv;
#pragma unroll
        for (int n = 0; n < NS; n++) {
            float aa = __expf(dtv * Av[n]);
            p[n] *= aa;
            u[n] = fmaf(aa, u[n], dx * BC[s][DTR + n]);
        }
    }
    ll o = (((ll)b * NCHUNK + c) * DI + d) * NS;
#pragma unroll
    for (int n = 0; n < NS; n++) { pA[o + n] = p[n]; U[o + n] = u[n]; }
}

// pass 2: combine over chunks; hst aliases U (read U before write)
__global__ __launch_bounds__(256) void scan2_k(const float* __restrict__ pA,
                                               const float* __restrict__ U,
                                               float* __restrict__ hst) {
    int i = blockIdx.x * 256 + threadIdx.x;  // b*(DI*NS) + d*NS + n
    int b = i >> 14;
    int rest = i & 16383;
    float h = 0.f;
#pragma unroll
    for (int c = 0; c < NCHUNK; c++) {
        ll o = ((ll)b * NCHUNK + c) * (DI * NS) + rest;
        float pa = pA[o], u = U[o];
        hst[o] = h;
        h = fmaf(pa, h, u);
    }
}

// pass 3: replay with true initial h; inline dt; fuse D_skip + silu(z); bf16 y out
__global__ __launch_bounds__(256) void scan3_k(const float* __restrict__ xc,
                                               const float* __restrict__ xdbl,
                                               const u16* __restrict__ xzb,
                                               const float* __restrict__ dtw,
                                               const float* __restrict__ dtb_,
                                               const float* __restrict__ A_log,
                                               const float* __restrict__ Dk,
                                               const float* __restrict__ hst,
                                               u16* __restrict__ y) {
    int blk = blockIdx.x;
    int dblk = blk & 3;
    int c = (blk >> 2) & (NCHUNK - 1);
    int b = blk >> 8;
    int d = dblk * 256 + threadIdx.x;
    int t0 = c * TCHUNK;
    __shared__ float BC[TCHUNK][64];
    {
        int rr = threadIdx.x >> 4, cc = (threadIdx.x & 15) << 2;
        *(float4*)&BC[rr][cc] = *(const float4*)&xdbl[((ll)(b * T_SZ + t0 + rr)) * 64 + cc];
    }
    float wd[DTR];
#pragma unroll
    for (int k4 = 0; k4 < 8; k4++) {
        float4 w4 = *(const float4*)&dtw[d * DTR + (k4 << 2)];
        wd[(k4 << 2) + 0] = w4.x; wd[(k4 << 2) + 1] = w4.y;
        wd[(k4 << 2) + 2] = w4.z; wd[(k4 << 2) + 3] = w4.w;
    }
    float bias = dtb_[d];
    float Av[NS];
#pragma unroll
    for (int n4 = 0; n4 < 4; n4++) {
        float4 alv = *(const float4*)&A_log[d * NS + (n4 << 2)];
        Av[(n4 << 2) + 0] = -__expf(alv.x); Av[(n4 << 2) + 1] = -__expf(alv.y);
        Av[(n4 << 2) + 2] = -__expf(alv.z); Av[(n4 << 2) + 3] = -__expf(alv.w);
    }
    float h[NS];
    ll ho = (((ll)b * NCHUNK + c) * DI + d) * NS;
#pragma unroll
    for (int n = 0; n < NS; n++) h[n] = hst[ho + n];
    float Dv = Dk[d];
    __syncthreads();
#pragma unroll
    for (int s = 0; s < TCHUNK; s++) {
        ll ro = (ll)(b * T_SZ + t0 + s);
        float adt = bias;
#pragma unroll
        for (int k = 0; k < DTR; k++) adt = fmaf(BC[s][k], wd[k], adt);
        float dtv = softplusf(adt);
        float xv = xc[ro * DI + d];
        float dx = dtv * xv;
        float acc = 0.f;
#pragma unroll
        for (int n = 0; n < NS; n++) {
            float aa = __expf(dtv * Av[n]);
            h[n] = fmaf(aa, h[n], dx * BC[s][DTR + n]);
            acc = fmaf(h[n], BC[s][DTR + NS + n], acc);
        }
        float zv = bf2f(xzb[ro * (2 * DI) + DI + d]);
        y[ro * DI + d] = f2bf((acc + xv * Dv) * siluf(zv));
    }
}

extern "C" void kernel_launch(void* const* d_in, const int* in_sizes, int n_in,
                              void* d_out, int out_size, void* d_ws, size_t ws_size,
                              hipStream_t stream) {
    const int*   codes   = (const int*)d_in[0];
    const float* embed_w = (const float*)d_in[1];
    const float* norm_w  = (const float*)d_in[2];
    const float* in_w    = (const float*)d_in[3];
    const float* conv_w  = (const float*)d_in[4];
    const float* conv_b  = (const float*)d_in[5];
    const float* xp_w    = (const float*)d_in[6];
    const float* dtp_w   = (const float*)d_in[7];
    const float* dtp_b   = (const float*)d_in[8];
    const float* A_log   = (const float*)d_in[9];
    const float* D_skip  = (const float*)d_in[10];
    const float* out_w   = (const float*)d_in[11];
    const float* head_w  = (const float*)d_in[12];
    float* out = (float*)d_out;

    float* ws = (float*)d_ws;
    float* x    = ws;                  // 1,048,576 f32
    float* xc   = x + 1048576;         // 2,097,152
    float* xdbl = xc + 2097152;        // 131,072
    float* pA   = xdbl + 131072;       // 2,097,152
    float* Uh   = pA + 2097152;        // 2,097,152 (U, then hst in-place)

    u16* us       = (u16*)(Uh + 2097152);
    u16* xz_bf    = us;                 // 4,194,304
    u16* xc_bf    = xz_bf + 4194304;    // 2,097,152 (x_bf shares first 1M, disjoint lifetime)
    u16* ybxn_bf  = xc_bf + 2097152;    // 2,097,152 (y_bf full; xn_bf shares first 1M)
    u16* w_in_bf  = ybxn_bf + 2097152;  // 2,097,152
    u16* w_xp_bf  = w_in_bf + 2097152;  // 131,072
    u16* w_out_bf = w_xp_bf + 131072;   // 1,048,576
    u16* w_hd_bf  = w_out_bf + 1048576; // 2,097,152  ([4096][512])

    u16* xn_bf = ybxn_bf;
    u16* y_bf  = ybxn_bf;
    u16* x_bf  = xc_bf;

    // setup: weight conversions + head transpose + embed/rmsnorm, one dispatch
    mega0_k<<<5760, 256, 0, stream>>>(in_w, xp_w, out_w, w_in_bf, w_xp_bf, w_out_bf,
                                      head_w, w_hd_bf, codes, embed_w, norm_w, x, xn_bf);

    for (int l = 0; l < 2; l++) {
        if (l == 1)
            rmsnorm_k<<<2048, 256, 0, stream>>>(x, norm_w + DM, xn_bf);
        // xz = xn @ in_w^T : (2048 x 2048), K=512 -> bf16.  grid 512 = 2 blk/CU
        mgemm3_k<0><<<dim3(32, 16), 256, 0, stream>>>(xn_bf, DM, w_in_bf + l * 1048576,
                                                      nullptr, xz_bf, 2 * DI, DM);
        conv_k<<<2048, 256, 0, stream>>>(xz_bf, conv_w + l * DI * 4, conv_b + l * DI, xc, xc_bf);
        // x_dbl = xc @ xp_w^T : (2048 x 64), K=1024 -> f32
        mgemm_k<1><<<dim3(1, 32), 256, 0, stream>>>(xc_bf, DI, w_xp_bf + l * 65536,
                                                    xdbl, 64, DI, nullptr, 0);
        scan1_k<<<512, 256, 0, stream>>>(xc, xdbl, dtp_w + l * DI * DTR, dtp_b + l * DI,
                                         A_log + l * DI * NS, pA, Uh);
        scan2_k<<<128, 256, 0, stream>>>(pA, Uh, Uh);
        scan3_k<<<512, 256, 0, stream>>>(xc, xdbl, xz_bf, dtp_w + l * DI * DTR, dtp_b + l * DI,
                                         A_log + l * DI * NS, D_skip + l * DI, Uh, y_bf);
        // x += y @ out_w^T : (2048 x 512), K=1024; also x_bf = bf16(x)
        mgemm_k<3><<<dim3(8, 32), 256, 0, stream>>>(y_bf, DI, w_out_bf + l * 524288,
                                                    x, DM, DI, x_bf, DM);
    }

    // head: out[b,z,t,v], single GEMM M=2048 x N=4096 x K=512.  grid 1024 = 4 blk/CU
    mgemm3_k<4><<<dim3(64, 16), 256, 0, stream>>>(x_bf, DM, w_hd_bf, out, nullptr, 0, DM);
}

// Round 7
// 329.471 us; speedup vs baseline: 1.0856x; 1.0856x over previous
//
#include <hip/hip_runtime.h>
#include <hip/hip_bf16.h>

// MambaLM: B=2,K=4,T=1024,V=1024, d_model=512, d_inner=1024, N=16, dt_rank=32, L=2
// R7: revert R6's scan dt-fusion (latency regression) + 128x64 tiles; keep merged
// setup kernel and single-dispatch head (128x128, 512 blocks = 2 blk/CU).

#define B_SZ 2
#define K_CB 4
#define T_SZ 1024
#define V_SZ 1024
#define DM 512
#define DI 1024
#define NS 16
#define DTR 32
#define NCHUNK 64
#define TCHUNK 16

typedef unsigned short u16;
typedef long long ll;
using short8 = __attribute__((ext_vector_type(8))) short;
using f32x4  = __attribute__((ext_vector_type(4))) float;

__device__ __forceinline__ float bf2f(u16 u) {
    union { unsigned int i; float f; } v; v.i = ((unsigned int)u) << 16; return v.f;
}
__device__ __forceinline__ u16 f2bf(float f) {
    union { float f; unsigned int i; } v; v.f = f;
    unsigned int x = v.i;
    return (u16)((x + 0x7fffu + ((x >> 16) & 1u)) >> 16);
}
__device__ __forceinline__ float siluf(float x) { return x / (1.f + __expf(-x)); }
__device__ __forceinline__ float softplusf(float x) { return (x > 20.f) ? x : log1pf(__expf(x)); }

__device__ __forceinline__ void gld16(const void* g, void* l) {
    __builtin_amdgcn_global_load_lds(
        (const __attribute__((address_space(1))) unsigned int*)g,
        (__attribute__((address_space(3))) unsigned int*)l, 16, 0, 0);
}

// ---------------- mega setup: weight cvt (3264 blk) + head transpose (512 blk)
//                  + embed+rmsnorm (2048 blk) ----------------
__global__ __launch_bounds__(256) void mega0_k(const float* __restrict__ in_w,
                                               const float* __restrict__ xp_w,
                                               const float* __restrict__ dtp_w,
                                               const float* __restrict__ out_w,
                                               u16* __restrict__ w_in, u16* __restrict__ w_xp,
                                               u16* __restrict__ w_dt, u16* __restrict__ w_out,
                                               const float* __restrict__ head_w,
                                               u16* __restrict__ w_hd,
                                               const int* __restrict__ codes,
                                               const float* __restrict__ ew,
                                               const float* __restrict__ nw,
                                               float* __restrict__ x,
                                               u16* __restrict__ xn) {
    __shared__ float tile[64][65];
    int bid = blockIdx.x;
    int tid = threadIdx.x;
    if (bid < 3264) {
        // flat f32->bf16: in_w (2097152) | xp_w (131072) | dtp_w (65536) | out_w (1048576)
        int i = (bid * 256 + tid) << 2;
        const float* s; u16* d;
        if (i < 2097152) { s = in_w + i; d = w_in + i; }
        else {
            i -= 2097152;
            if (i < 131072) { s = xp_w + i; d = w_xp + i; }
            else {
                i -= 131072;
                if (i < 65536) { s = dtp_w + i; d = w_dt + i; }
                else { i -= 65536; s = out_w + i; d = w_out + i; }
            }
        }
        float4 v = *(const float4*)s;
        ushort4 o; o.x = f2bf(v.x); o.y = f2bf(v.y); o.z = f2bf(v.z); o.w = f2bf(v.w);
        *(ushort4*)d = o;
    } else if (bid < 3776) {
        // head transpose: w[4][512][1024] f32 -> wt[4][1024][512] bf16
        int idx = bid - 3264;
        int z = idx >> 7, rest = idx & 127;
        int d0 = (rest >> 4) << 6, v0 = (rest & 15) << 6;
        int col = tid & 63, rbase = tid >> 6;
#pragma unroll
        for (int i = 0; i < 16; i++) {
            int row = (i << 2) + rbase;
            tile[row][col] = head_w[(ll)z * (DM * V_SZ) + (ll)(d0 + row) * V_SZ + v0 + col];
        }
        __syncthreads();
#pragma unroll
        for (int i = 0; i < 16; i++) {
            int vrow = (i << 2) + rbase;
            w_hd[(ll)z * (V_SZ * DM) + (ll)(v0 + vrow) * DM + d0 + col] = f2bf(tile[col][vrow]);
        }
    } else {
        // embedding + rmsnorm (layer-0 input)
        int row = bid - 3776;  // b*1024 + t
        int b = row >> 10, t = row & 1023;
        float a0 = 0.f, a1 = 0.f;
#pragma unroll
        for (int k = 0; k < K_CB; k++) {
            int c = codes[b * (K_CB * T_SZ) + k * T_SZ + t];
            a0 += ew[((ll)k * V_SZ + c) * DM + tid];
            a1 += ew[((ll)k * V_SZ + c) * DM + tid + 256];
        }
        x[(ll)row * DM + tid]       = a0;
        x[(ll)row * DM + tid + 256] = a1;
        float ss = a0 * a0 + a1 * a1;
#pragma unroll
        for (int off = 32; off > 0; off >>= 1) ss += __shfl_down(ss, off, 64);
        float* red = &tile[0][0];
        if ((tid & 63) == 0) red[tid >> 6] = ss;
        __syncthreads();
        float tot = red[0] + red[1] + red[2] + red[3];
        float scale = rsqrtf(tot * (1.0f / DM) + 1e-6f);
        xn[(ll)row * DM + tid]       = f2bf(a0 * scale * nw[tid]);
        xn[(ll)row * DM + tid + 256] = f2bf(a1 * scale * nw[tid + 256]);
    }
}

// ---------------- rmsnorm (layer 1): f32 in -> bf16 out ----------------
__global__ __launch_bounds__(256) void rmsnorm_k(const float* __restrict__ x,
                                                 const float* __restrict__ w,
                                                 u16* __restrict__ xn) {
    ll row = blockIdx.x;
    const float* xr = x + row * DM;
    int tid = threadIdx.x;
    float v0 = xr[tid], v1 = xr[tid + 256];
    float ss = v0 * v0 + v1 * v1;
#pragma unroll
    for (int off = 32; off > 0; off >>= 1) ss += __shfl_down(ss, off, 64);
    __shared__ float red[4];
    if ((tid & 63) == 0) red[tid >> 6] = ss;
    __syncthreads();
    float tot = red[0] + red[1] + red[2] + red[3];
    float scale = rsqrtf(tot * (1.0f / DM) + 1e-6f);
    xn[row * DM + tid]       = f2bf(v0 * scale * w[tid]);
    xn[row * DM + tid + 256] = f2bf(v1 * scale * w[tid + 256]);
}

// ---------------- 128x128 MFMA GEMM, global_load_lds staging (m97 structure) ----------------
// C[M,N] = A[M,K](bf16) * W[N,K](bf16)^T.  4 waves 2x2 -> each wave 64x64 = 4x4 mfma tiles.
// EP0: bf16 store Cb (in_proj).  EP4: head f32 scatter, N=4096 (n -> z=n>>10, v=n&1023).
template <int EP>
__global__ __launch_bounds__(256) void mgemm2_k(const u16* __restrict__ A, int lda,
                                                const u16* __restrict__ W,
                                                float* __restrict__ C,
                                                u16* __restrict__ Cb, int ldcb, int K) {
    __shared__ u16 As[4096];   // [128][32]
    __shared__ u16 Bs[4096];
    int tid = threadIdx.x;
    int wave = tid >> 6, lane = tid & 63;
    int q = lane >> 4, r = lane & 15;
    int m0 = blockIdx.y << 7, n0 = blockIdx.x << 7;
    int wm = (wave >> 1) << 6, wn = (wave & 1) << 6;
    int sa0 = (wave << 7) + lane, sa1 = sa0 + 64;   // staging slots (row=s>>2, chunk=s&3)
    f32x4 acc[4][4];
#pragma unroll
    for (int i = 0; i < 4; i++)
#pragma unroll
        for (int j = 0; j < 4; j++) acc[i][j] = (f32x4){0.f, 0.f, 0.f, 0.f};

    for (int k0 = 0; k0 < K; k0 += 32) {
        gld16(A + (ll)(m0 + (sa0 >> 2)) * lda + k0 + ((sa0 & 3) << 3), &As[wave << 10]);
        gld16(A + (ll)(m0 + (sa1 >> 2)) * lda + k0 + ((sa1 & 3) << 3), &As[(wave << 10) + 512]);
        gld16(W + (ll)(n0 + (sa0 >> 2)) * K   + k0 + ((sa0 & 3) << 3), &Bs[wave << 10]);
        gld16(W + (ll)(n0 + (sa1 >> 2)) * K   + k0 + ((sa1 & 3) << 3), &Bs[(wave << 10) + 512]);
        __syncthreads();
        short8 af[4], bfr[4];
#pragma unroll
        for (int i = 0; i < 4; i++) af[i]  = *(const short8*)&As[((wm + (i << 4) + r) << 5) + (q << 3)];
#pragma unroll
        for (int j = 0; j < 4; j++) bfr[j] = *(const short8*)&Bs[((wn + (j << 4) + r) << 5) + (q << 3)];
#pragma unroll
        for (int i = 0; i < 4; i++)
#pragma unroll
            for (int j = 0; j < 4; j++)
                acc[i][j] = __builtin_amdgcn_mfma_f32_16x16x32_bf16(af[i], bfr[j], acc[i][j], 0, 0, 0);
        __syncthreads();
    }

#pragma unroll
    for (int i = 0; i < 4; i++)
#pragma unroll
        for (int j = 0; j < 4; j++)
#pragma unroll
            for (int g = 0; g < 4; g++) {
                int m = m0 + wm + (i << 4) + (q << 2) + g;
                int n = n0 + wn + (j << 4) + r;
                float v = acc[i][j][g];
                if (EP == 0) {
                    Cb[(ll)m * ldcb + n] = f2bf(v);
                } else {
                    int z = n >> 10, vv = n & 1023;
                    int b = m >> 10, t = m & 1023;
                    C[((ll)(b * K_CB + z) * T_SZ + t) * V_SZ + vv] = v;
                }
            }
}

// ---------------- 64x64 MFMA GEMM (small shapes) ----------------
// EP1: f32 + bf16 store (x_proj).  EP2: softplus(acc+bias[n]) f32 (dt_proj).
// EP3: C += acc, Cb = bf16(C) (out_proj).
template <int EP>
__global__ __launch_bounds__(256) void mgemm_k(const u16* __restrict__ A, int lda,
                                               const u16* __restrict__ W,
                                               float* __restrict__ C, int ldc, int K,
                                               const float* __restrict__ bias,
                                               u16* __restrict__ Cb, int ldcb) {
    __shared__ u16 As[64][40];
    __shared__ u16 Bs[64][40];
    int tid = threadIdx.x;
    int m0 = blockIdx.y << 6, n0 = blockIdx.x << 6;
    int lane = tid & 63, wave = tid >> 6;
    int q = lane >> 4, r = lane & 15;
    int wm = (wave >> 1) << 5, wn = (wave & 1) << 5;
    int srow = tid >> 2, sseg = (tid & 3) << 3;
    f32x4 acc[2][2];
#pragma unroll
    for (int i = 0; i < 2; i++)
#pragma unroll
        for (int j = 0; j < 2; j++) acc[i][j] = (f32x4){0.f, 0.f, 0.f, 0.f};

    for (int k0 = 0; k0 < K; k0 += 32) {
        *(uint4*)&As[srow][sseg] = *(const uint4*)&A[(ll)(m0 + srow) * lda + k0 + sseg];
        *(uint4*)&Bs[srow][sseg] = *(const uint4*)&W[(ll)(n0 + srow) * K + k0 + sseg];
        __syncthreads();
        short8 af[2], bfr[2];
#pragma unroll
        for (int i = 0; i < 2; i++) af[i]  = *(const short8*)&As[wm + (i << 4) + r][q << 3];
#pragma unroll
        for (int j = 0; j < 2; j++) bfr[j] = *(const short8*)&Bs[wn + (j << 4) + r][q << 3];
#pragma unroll
        for (int i = 0; i < 2; i++)
#pragma unroll
            for (int j = 0; j < 2; j++)
                acc[i][j] = __builtin_amdgcn_mfma_f32_16x16x32_bf16(af[i], bfr[j], acc[i][j], 0, 0, 0);
        __syncthreads();
    }

#pragma unroll
    for (int i = 0; i < 2; i++)
#pragma unroll
        for (int j = 0; j < 2; j++)
#pragma unroll
            for (int g = 0; g < 4; g++) {
                int m = m0 + wm + (i << 4) + (q << 2) + g;
                int n = n0 + wn + (j << 4) + r;
                float v = acc[i][j][g];
                if (EP == 1) {
                    C[(ll)m * ldc + n] = v;
                    Cb[(ll)m * ldcb + n] = f2bf(v);
                } else if (EP == 2) {
                    C[(ll)m * ldc + n] = softplusf(v + bias[n]);
                } else {
                    float nv = C[(ll)m * ldc + n] + v;
                    C[(ll)m * ldc + n] = nv;
                    Cb[(ll)m * ldcb + n] = f2bf(nv);
                }
            }
}

// ---------------- causal dwconv(4) + bias + silu, ushort4-vectorized ----------------
__global__ __launch_bounds__(256) void conv_k(const u16* __restrict__ xzb,
                                              const float* __restrict__ cw,
                                              const float* __restrict__ cb,
                                              float* __restrict__ xc,
                                              u16* __restrict__ xcb) {
    int row = blockIdx.x;  // b*1024+t
    int b = row >> 10, t = row & 1023;
    int c0 = threadIdx.x << 2;
    float4 a = *(const float4*)&cb[c0];
    float acc[4] = {a.x, a.y, a.z, a.w};
    float4 cwv[4];
#pragma unroll
    for (int e = 0; e < 4; e++) cwv[e] = *(const float4*)&cw[(c0 + e) << 2];
#pragma unroll
    for (int j = 0; j < 4; j++) {
        int tt = t - 3 + j;
        if (tt >= 0) {
            ushort4 v = *(const ushort4*)&xzb[((ll)(b * T_SZ + tt)) * (2 * DI) + c0];
            acc[0] = fmaf(bf2f(v.x), ((const float*)&cwv[0])[j], acc[0]);
            acc[1] = fmaf(bf2f(v.y), ((const float*)&cwv[1])[j], acc[1]);
            acc[2] = fmaf(bf2f(v.z), ((const float*)&cwv[2])[j], acc[2]);
            acc[3] = fmaf(bf2f(v.w), ((const float*)&cwv[3])[j], acc[3]);
        }
    }
    float4 s; ushort4 sb;
    s.x = siluf(acc[0]); s.y = siluf(acc[1]); s.z = siluf(acc[2]); s.w = siluf(acc[3]);
    sb.x = f2bf(s.x); sb.y = f2bf(s.y); sb.z = f2bf(s.z); sb.w = f2bf(s.w);
    *(float4*)&xc[(ll)row * DI + c0] = s;
    *(ushort4*)&xcb[(ll)row * DI + c0] = sb;
}

// ---------------- chunked selective scan ----------------
// pass 1: per-chunk (prodA, U). grid = B*NCHUNK*(DI/256) = 512 blocks
__global__ __launch_bounds__(256) void scan1_k(const float* __restrict__ dt,
                                               const float* __restrict__ xc,
                                               const float* __restrict__ xdbl,
                                               const float* __restrict__ A_log,
                                               float* __restrict__ pA, float* __restrict__ U) {
    int blk = blockIdx.x;
    int dblk = blk & 3;
    int c = (blk >> 2) & (NCHUNK - 1);
    int b = blk >> 8;
    int d = dblk * 256 + threadIdx.x;
    int t0 = c * TCHUNK;
    __shared__ float BC[TCHUNK][32];
    if (threadIdx.x < TCHUNK * 8) {
        int rr = threadIdx.x >> 3, cc = (threadIdx.x & 7) << 2;
        *(float4*)&BC[rr][cc] = *(const float4*)&xdbl[((ll)(b * T_SZ + t0 + rr)) * 64 + DTR + cc];
    }
    float Av[NS];
#pragma unroll
    for (int n4 = 0; n4 < 4; n4++) {
        float4 alv = *(const float4*)&A_log[d * NS + (n4 << 2)];
        Av[(n4 << 2) + 0] = -__expf(alv.x); Av[(n4 << 2) + 1] = -__expf(alv.y);
        Av[(n4 << 2) + 2] = -__expf(alv.z); Av[(n4 << 2) + 3] = -__expf(alv.w);
    }
    __syncthreads();
    float p[NS], u[NS];
#pragma unroll
    for (int n = 0; n < NS; n++) { p[n] = 1.f; u[n] = 0.f; }
#pragma unroll
    for (int s = 0; s < TCHUNK; s++) {
        ll ro = (ll)(b * T_SZ + t0 + s);
        float dtv = dt[ro * DI + d];
        float xv = xc[ro * DI + d];
        float dx = dtv * xv;
#pragma unroll
        for (int n = 0; n < NS; n++) {
            float aa = __expf(dtv * Av[n]);
            p[n] *= aa;
            u[n] = fmaf(aa, u[n], dx * BC[s][n]);
        }
    }
    ll o = (((ll)b * NCHUNK + c) * DI + d) * NS;
#pragma unroll
    for (int n = 0; n < NS; n++) { pA[o + n] = p[n]; U[o + n] = u[n]; }
}

// pass 2: combine over chunks; hst aliases U (read U before write)
__global__ __launch_bounds__(256) void scan2_k(const float* __restrict__ pA,
                                               const float* __restrict__ U,
                                               float* __restrict__ hst) {
    int i = blockIdx.x * 256 + threadIdx.x;  // b*(DI*NS) + d*NS + n
    int b = i >> 14;
    int rest = i & 16383;
    float h = 0.f;
#pragma unroll
    for (int c = 0; c < NCHUNK; c++) {
        ll o = ((ll)b * NCHUNK + c) * (DI * NS) + rest;
        float pa = pA[o], u = U[o];
        hst[o] = h;
        h = fmaf(pa, h, u);
    }
}

// pass 3: replay with true initial h; fuse D_skip + silu(z) gate; bf16 y out
__global__ __launch_bounds__(256) void scan3_k(const float* __restrict__ dt,
                                               const float* __restrict__ xc,
                                               const float* __restrict__ xdbl,
                                               const u16* __restrict__ xzb,
                                               const float* __restrict__ A_log,
                                               const float* __restrict__ Dk,
                                               const float* __restrict__ hst,
                                               u16* __restrict__ y) {
    int blk = blockIdx.x;
    int dblk = blk & 3;
    int c = (blk >> 2) & (NCHUNK - 1);
    int b = blk >> 8;
    int d = dblk * 256 + threadIdx.x;
    int t0 = c * TCHUNK;
    __shared__ float BC[TCHUNK][32];
    if (threadIdx.x < TCHUNK * 8) {
        int rr = threadIdx.x >> 3, cc = (threadIdx.x & 7) << 2;
        *(float4*)&BC[rr][cc] = *(const float4*)&xdbl[((ll)(b * T_SZ + t0 + rr)) * 64 + DTR + cc];
    }
    float Av[NS];
#pragma unroll
    for (int n4 = 0; n4 < 4; n4++) {
        float4 alv = *(const float4*)&A_log[d * NS + (n4 << 2)];
        Av[(n4 << 2) + 0] = -__expf(alv.x); Av[(n4 << 2) + 1] = -__expf(alv.y);
        Av[(n4 << 2) + 2] = -__expf(alv.z); Av[(n4 << 2) + 3] = -__expf(alv.w);
    }
    float h[NS];
    ll ho = (((ll)b * NCHUNK + c) * DI + d) * NS;
#pragma unroll
    for (int n = 0; n < NS; n++) h[n] = hst[ho + n];
    float Dv = Dk[d];
    __syncthreads();
#pragma unroll
    for (int s = 0; s < TCHUNK; s++) {
        ll ro = (ll)(b * T_SZ + t0 + s);
        float dtv = dt[ro * DI + d];
        float xv = xc[ro * DI + d];
        float dx = dtv * xv;
        float acc = 0.f;
#pragma unroll
        for (int n = 0; n < NS; n++) {
            float aa = __expf(dtv * Av[n]);
            h[n] = fmaf(aa, h[n], dx * BC[s][n]);
            acc = fmaf(h[n], BC[s][16 + n], acc);
        }
        float zv = bf2f(xzb[ro * (2 * DI) + DI + d]);
        y[ro * DI + d] = f2bf((acc + xv * Dv) * siluf(zv));
    }
}

extern "C" void kernel_launch(void* const* d_in, const int* in_sizes, int n_in,
                              void* d_out, int out_size, void* d_ws, size_t ws_size,
                              hipStream_t stream) {
    const int*   codes   = (const int*)d_in[0];
    const float* embed_w = (const float*)d_in[1];
    const float* norm_w  = (const float*)d_in[2];
    const float* in_w    = (const float*)d_in[3];
    const float* conv_w  = (const float*)d_in[4];
    const float* conv_b  = (const float*)d_in[5];
    const float* xp_w    = (const float*)d_in[6];
    const float* dtp_w   = (const float*)d_in[7];
    const float* dtp_b   = (const float*)d_in[8];
    const float* A_log   = (const float*)d_in[9];
    const float* D_skip  = (const float*)d_in[10];
    const float* out_w   = (const float*)d_in[11];
    const float* head_w  = (const float*)d_in[12];
    float* out = (float*)d_out;

    float* ws = (float*)d_ws;
    float* x    = ws;                  // 1,048,576 f32
    float* xc   = x + 1048576;         // 2,097,152
    float* dtb  = xc + 2097152;        // 2,097,152
    float* xdbl = dtb + 2097152;       // 131,072
    float* pA   = xdbl + 131072;       // 2,097,152
    float* Uh   = pA + 2097152;        // 2,097,152 (U, then hst in-place)

    u16* us       = (u16*)(Uh + 2097152);
    u16* xz_bf    = us;                 // 4,194,304
    u16* xc_bf    = xz_bf + 4194304;    // 2,097,152 (x_bf shares first 1M, disjoint lifetime)
    u16* ybxn_bf  = xc_bf + 2097152;    // 2,097,152 (y_bf full; xn_bf shares first 1M)
    u16* xdbl_bf  = ybxn_bf + 2097152;  // 131,072
    u16* w_in_bf  = xdbl_bf + 131072;   // 2,097,152
    u16* w_xp_bf  = w_in_bf + 2097152;  // 131,072
    u16* w_dt_bf  = w_xp_bf + 131072;   // 65,536
    u16* w_out_bf = w_dt_bf + 65536;    // 1,048,576
    u16* w_hd_bf  = w_out_bf + 1048576; // 2,097,152 ([4096][512])

    u16* xn_bf = ybxn_bf;
    u16* y_bf  = ybxn_bf;
    u16* x_bf  = xc_bf;

    // setup: weight conversions + head transpose + embed/rmsnorm, one dispatch
    mega0_k<<<5824, 256, 0, stream>>>(in_w, xp_w, dtp_w, out_w,
                                      w_in_bf, w_xp_bf, w_dt_bf, w_out_bf,
                                      head_w, w_hd_bf, codes, embed_w, norm_w, x, xn_bf);

    for (int l = 0; l < 2; l++) {
        const float* al = A_log + l * DI * NS;
        if (l == 1)
            rmsnorm_k<<<2048, 256, 0, stream>>>(x, norm_w + DM, xn_bf);
        // xz = xn @ in_w^T : (2048 x 2048), K=512 -> bf16.  128x128 tiles, 256 blocks
        mgemm2_k<0><<<dim3(16, 16), 256, 0, stream>>>(xn_bf, DM, w_in_bf + l * 1048576,
                                                      nullptr, xz_bf, 2 * DI, DM);
        conv_k<<<2048, 256, 0, stream>>>(xz_bf, conv_w + l * DI * 4, conv_b + l * DI, xc, xc_bf);
        // x_dbl = xc @ xp_w^T : (2048 x 64), K=1024 -> f32 + bf16
        mgemm_k<1><<<dim3(1, 32), 256, 0, stream>>>(xc_bf, DI, w_xp_bf + l * 65536,
                                                    xdbl, 64, DI, nullptr, xdbl_bf, 64);
        // dt = softplus(x_dbl[:, :32] @ dtp_w^T + b) : (2048 x 1024), K=32
        mgemm_k<2><<<dim3(16, 32), 256, 0, stream>>>(xdbl_bf, 64, w_dt_bf + l * 32768,
                                                     dtb, DI, DTR, dtp_b + l * DI, nullptr, 0);
        scan1_k<<<512, 256, 0, stream>>>(dtb, xc, xdbl, al, pA, Uh);
        scan2_k<<<128, 256, 0, stream>>>(pA, Uh, Uh);
        scan3_k<<<512, 256, 0, stream>>>(dtb, xc, xdbl, xz_bf, al, D_skip + l * DI, Uh, y_bf);
        // x += y @ out_w^T : (2048 x 512), K=1024; also x_bf = bf16(x)
        mgemm_k<3><<<dim3(8, 32), 256, 0, stream>>>(y_bf, DI, w_out_bf + l * 524288,
                                                    x, DM, DI, nullptr, x_bf, DM);
    }

    // head: single GEMM M=2048 x N=4096 x K=512, 128x128 tiles, 512 blocks = 2 blk/CU
    mgemm2_k<4><<<dim3(32, 16), 256, 0, stream>>>(x_bf, DM, w_hd_bf, out, nullptr, 0, DM);
}

// Round 8
// 305.692 us; speedup vs baseline: 1.1700x; 1.0778x over previous
//
#include <hip/hip_runtime.h>
#include <hip/hip_bf16.h>

// MambaLM: B=2,K=4,T=1024,V=1024, d_model=512, d_inner=1024, N=16, dt_rank=32, L=2
// R8 = R7 + software-pipelined MFMA GEMMs (register prefetch + dual LDS buffers,
// ONE barrier per K-iter) for all GEMM kernels. At 1 blk/CU the m97 2-barrier
// structure serially exposes the vmcnt(0) drain; pipelining hides it behind MFMAs.

#define B_SZ 2
#define K_CB 4
#define T_SZ 1024
#define V_SZ 1024
#define DM 512
#define DI 1024
#define NS 16
#define DTR 32
#define NCHUNK 64
#define TCHUNK 16

typedef unsigned short u16;
typedef long long ll;
using short8 = __attribute__((ext_vector_type(8))) short;
using f32x4  = __attribute__((ext_vector_type(4))) float;

__device__ __forceinline__ float bf2f(u16 u) {
    union { unsigned int i; float f; } v; v.i = ((unsigned int)u) << 16; return v.f;
}
__device__ __forceinline__ u16 f2bf(float f) {
    union { float f; unsigned int i; } v; v.f = f;
    unsigned int x = v.i;
    return (u16)((x + 0x7fffu + ((x >> 16) & 1u)) >> 16);
}
__device__ __forceinline__ float siluf(float x) { return x / (1.f + __expf(-x)); }
__device__ __forceinline__ float softplusf(float x) { return (x > 20.f) ? x : log1pf(__expf(x)); }

// ---------------- mega setup: weight cvt (3264 blk) + head transpose (512 blk)
//                  + embed+rmsnorm (2048 blk) ----------------
__global__ __launch_bounds__(256) void mega0_k(const float* __restrict__ in_w,
                                               const float* __restrict__ xp_w,
                                               const float* __restrict__ dtp_w,
                                               const float* __restrict__ out_w,
                                               u16* __restrict__ w_in, u16* __restrict__ w_xp,
                                               u16* __restrict__ w_dt, u16* __restrict__ w_out,
                                               const float* __restrict__ head_w,
                                               u16* __restrict__ w_hd,
                                               const int* __restrict__ codes,
                                               const float* __restrict__ ew,
                                               const float* __restrict__ nw,
                                               float* __restrict__ x,
                                               u16* __restrict__ xn) {
    __shared__ float tile[64][65];
    int bid = blockIdx.x;
    int tid = threadIdx.x;
    if (bid < 3264) {
        // flat f32->bf16: in_w (2097152) | xp_w (131072) | dtp_w (65536) | out_w (1048576)
        int i = (bid * 256 + tid) << 2;
        const float* s; u16* d;
        if (i < 2097152) { s = in_w + i; d = w_in + i; }
        else {
            i -= 2097152;
            if (i < 131072) { s = xp_w + i; d = w_xp + i; }
            else {
                i -= 131072;
                if (i < 65536) { s = dtp_w + i; d = w_dt + i; }
                else { i -= 65536; s = out_w + i; d = w_out + i; }
            }
        }
        float4 v = *(const float4*)s;
        ushort4 o; o.x = f2bf(v.x); o.y = f2bf(v.y); o.z = f2bf(v.z); o.w = f2bf(v.w);
        *(ushort4*)d = o;
    } else if (bid < 3776) {
        // head transpose: w[4][512][1024] f32 -> wt[4][1024][512] bf16
        int idx = bid - 3264;
        int z = idx >> 7, rest = idx & 127;
        int d0 = (rest >> 4) << 6, v0 = (rest & 15) << 6;
        int col = tid & 63, rbase = tid >> 6;
#pragma unroll
        for (int i = 0; i < 16; i++) {
            int row = (i << 2) + rbase;
            tile[row][col] = head_w[(ll)z * (DM * V_SZ) + (ll)(d0 + row) * V_SZ + v0 + col];
        }
        __syncthreads();
#pragma unroll
        for (int i = 0; i < 16; i++) {
            int vrow = (i << 2) + rbase;
            w_hd[(ll)z * (V_SZ * DM) + (ll)(v0 + vrow) * DM + d0 + col] = f2bf(tile[col][vrow]);
        }
    } else {
        // embedding + rmsnorm (layer-0 input)
        int row = bid - 3776;  // b*1024 + t
        int b = row >> 10, t = row & 1023;
        float a0 = 0.f, a1 = 0.f;
#pragma unroll
        for (int k = 0; k < K_CB; k++) {
            int c = codes[b * (K_CB * T_SZ) + k * T_SZ + t];
            a0 += ew[((ll)k * V_SZ + c) * DM + tid];
            a1 += ew[((ll)k * V_SZ + c) * DM + tid + 256];
        }
        x[(ll)row * DM + tid]       = a0;
        x[(ll)row * DM + tid + 256] = a1;
        float ss = a0 * a0 + a1 * a1;
#pragma unroll
        for (int off = 32; off > 0; off >>= 1) ss += __shfl_down(ss, off, 64);
        float* red = &tile[0][0];
        if ((tid & 63) == 0) red[tid >> 6] = ss;
        __syncthreads();
        float tot = red[0] + red[1] + red[2] + red[3];
        float scale = rsqrtf(tot * (1.0f / DM) + 1e-6f);
        xn[(ll)row * DM + tid]       = f2bf(a0 * scale * nw[tid]);
        xn[(ll)row * DM + tid + 256] = f2bf(a1 * scale * nw[tid + 256]);
    }
}

// ---------------- rmsnorm (layer 1): f32 in -> bf16 out ----------------
__global__ __launch_bounds__(256) void rmsnorm_k(const float* __restrict__ x,
                                                 const float* __restrict__ w,
                                                 u16* __restrict__ xn) {
    ll row = blockIdx.x;
    const float* xr = x + row * DM;
    int tid = threadIdx.x;
    float v0 = xr[tid], v1 = xr[tid + 256];
    float ss = v0 * v0 + v1 * v1;
#pragma unroll
    for (int off = 32; off > 0; off >>= 1) ss += __shfl_down(ss, off, 64);
    __shared__ float red[4];
    if ((tid & 63) == 0) red[tid >> 6] = ss;
    __syncthreads();
    float tot = red[0] + red[1] + red[2] + red[3];
    float scale = rsqrtf(tot * (1.0f / DM) + 1e-6f);
    xn[row * DM + tid]       = f2bf(v0 * scale * w[tid]);
    xn[row * DM + tid + 256] = f2bf(v1 * scale * w[tid + 256]);
}

// ---------------- 128x128 MFMA GEMM, reg-prefetch + dual-LDS pipeline ----------------
// C[M,N] = A[M,K](bf16) * W[N,K](bf16)^T.  4 waves 2x2 -> each wave 64x64 = 4x4 mfma.
// One __syncthreads per K-iter; tile k+1 prefetched to VGPRs while MFMAs run on LDS[p].
// EP0: bf16 store Cb (in_proj).  EP4: head f32 scatter, N=4096 (z=n>>10, v=n&1023).
template <int EP>
__global__ __launch_bounds__(256) void mgemm2_k(const u16* __restrict__ A, int lda,
                                                const u16* __restrict__ W,
                                                float* __restrict__ C,
                                                u16* __restrict__ Cb, int ldcb, int K) {
    __shared__ u16 As[2][4096];   // [128][32] each
    __shared__ u16 Bs[2][4096];
    int tid = threadIdx.x;
    int wave = tid >> 6, lane = tid & 63;
    int q = lane >> 4, r = lane & 15;
    int m0 = blockIdx.y << 7, n0 = blockIdx.x << 7;
    int wm = (wave >> 1) << 6, wn = (wave & 1) << 6;
    int srow = tid >> 1, soff = (tid & 1) << 4;     // row 0..127, u16-offset 0/16
    const u16* Ap = A + (ll)(m0 + srow) * lda + soff;
    const u16* Wp = W + (ll)(n0 + srow) * K + soff;
    int sidx = (srow << 5) + soff;
    f32x4 acc[4][4];
#pragma unroll
    for (int i = 0; i < 4; i++)
#pragma unroll
        for (int j = 0; j < 4; j++) acc[i][j] = (f32x4){0.f, 0.f, 0.f, 0.f};

    uint4 ra0 = *(const uint4*)Ap,       ra1 = *(const uint4*)(Ap + 8);
    uint4 rb0 = *(const uint4*)Wp,       rb1 = *(const uint4*)(Wp + 8);
    *(uint4*)&As[0][sidx] = ra0; *(uint4*)&As[0][sidx + 8] = ra1;
    *(uint4*)&Bs[0][sidx] = rb0; *(uint4*)&Bs[0][sidx + 8] = rb1;
    __syncthreads();

    int p = 0;
    for (int k0 = 0; k0 < K; k0 += 32) {
        bool pf = (k0 + 32) < K;
        if (pf) {
            ra0 = *(const uint4*)(Ap + k0 + 32); ra1 = *(const uint4*)(Ap + k0 + 40);
            rb0 = *(const uint4*)(Wp + k0 + 32); rb1 = *(const uint4*)(Wp + k0 + 40);
        }
        short8 af[4], bfr[4];
#pragma unroll
        for (int i = 0; i < 4; i++) af[i]  = *(const short8*)&As[p][((wm + (i << 4) + r) << 5) + (q << 3)];
#pragma unroll
        for (int j = 0; j < 4; j++) bfr[j] = *(const short8*)&Bs[p][((wn + (j << 4) + r) << 5) + (q << 3)];
#pragma unroll
        for (int i = 0; i < 4; i++)
#pragma unroll
            for (int j = 0; j < 4; j++)
                acc[i][j] = __builtin_amdgcn_mfma_f32_16x16x32_bf16(af[i], bfr[j], acc[i][j], 0, 0, 0);
        if (pf) {
            *(uint4*)&As[p ^ 1][sidx] = ra0; *(uint4*)&As[p ^ 1][sidx + 8] = ra1;
            *(uint4*)&Bs[p ^ 1][sidx] = rb0; *(uint4*)&Bs[p ^ 1][sidx + 8] = rb1;
        }
        __syncthreads();
        p ^= 1;
    }

#pragma unroll
    for (int i = 0; i < 4; i++)
#pragma unroll
        for (int j = 0; j < 4; j++)
#pragma unroll
            for (int g = 0; g < 4; g++) {
                int m = m0 + wm + (i << 4) + (q << 2) + g;
                int n = n0 + wn + (j << 4) + r;
                float v = acc[i][j][g];
                if (EP == 0) {
                    Cb[(ll)m * ldcb + n] = f2bf(v);
                } else {
                    int z = n >> 10, vv = n & 1023;
                    int b = m >> 10, t = m & 1023;
                    C[((ll)(b * K_CB + z) * T_SZ + t) * V_SZ + vv] = v;
                }
            }
}

// ---------------- 64x64 MFMA GEMM, reg-prefetch + dual-LDS pipeline ----------------
// EP1: f32 + bf16 store (x_proj).  EP2: softplus(acc+bias[n]) f32 (dt_proj).
// EP3: C += acc, Cb = bf16(C) (out_proj).
template <int EP>
__global__ __launch_bounds__(256) void mgemm_k(const u16* __restrict__ A, int lda,
                                               const u16* __restrict__ W,
                                               float* __restrict__ C, int ldc, int K,
                                               const float* __restrict__ bias,
                                               u16* __restrict__ Cb, int ldcb) {
    __shared__ u16 As[2][2048];   // [64][32] each
    __shared__ u16 Bs[2][2048];
    int tid = threadIdx.x;
    int m0 = blockIdx.y << 6, n0 = blockIdx.x << 6;
    int lane = tid & 63, wave = tid >> 6;
    int q = lane >> 4, r = lane & 15;
    int wm = (wave >> 1) << 5, wn = (wave & 1) << 5;
    int srow = tid >> 2, soff = (tid & 3) << 3;     // row 0..63, u16-offset 0/8/16/24
    const u16* Ap = A + (ll)(m0 + srow) * lda + soff;
    const u16* Wp = W + (ll)(n0 + srow) * K + soff;
    int sidx = (srow << 5) + soff;
    f32x4 acc[2][2];
#pragma unroll
    for (int i = 0; i < 2; i++)
#pragma unroll
        for (int j = 0; j < 2; j++) acc[i][j] = (f32x4){0.f, 0.f, 0.f, 0.f};

    uint4 ra = *(const uint4*)Ap;
    uint4 rb = *(const uint4*)Wp;
    *(uint4*)&As[0][sidx] = ra;
    *(uint4*)&Bs[0][sidx] = rb;
    __syncthreads();

    int p = 0;
    for (int k0 = 0; k0 < K; k0 += 32) {
        bool pf = (k0 + 32) < K;
        if (pf) {
            ra = *(const uint4*)(Ap + k0 + 32);
            rb = *(const uint4*)(Wp + k0 + 32);
        }
        short8 af[2], bfr[2];
#pragma unroll
        for (int i = 0; i < 2; i++) af[i]  = *(const short8*)&As[p][((wm + (i << 4) + r) << 5) + (q << 3)];
#pragma unroll
        for (int j = 0; j < 2; j++) bfr[j] = *(const short8*)&Bs[p][((wn + (j << 4) + r) << 5) + (q << 3)];
#pragma unroll
        for (int i = 0; i < 2; i++)
#pragma unroll
            for (int j = 0; j < 2; j++)
                acc[i][j] = __builtin_amdgcn_mfma_f32_16x16x32_bf16(af[i], bfr[j], acc[i][j], 0, 0, 0);
        if (pf) {
            *(uint4*)&As[p ^ 1][sidx] = ra;
            *(uint4*)&Bs[p ^ 1][sidx] = rb;
        }
        __syncthreads();
        p ^= 1;
    }

#pragma unroll
    for (int i = 0; i < 2; i++)
#pragma unroll
        for (int j = 0; j < 2; j++)
#pragma unroll
            for (int g = 0; g < 4; g++) {
                int m = m0 + wm + (i << 4) + (q << 2) + g;
                int n = n0 + wn + (j << 4) + r;
                float v = acc[i][j][g];
                if (EP == 1) {
                    C[(ll)m * ldc + n] = v;
                    Cb[(ll)m * ldcb + n] = f2bf(v);
                } else if (EP == 2) {
                    C[(ll)m * ldc + n] = softplusf(v + bias[n]);
                } else {
                    float nv = C[(ll)m * ldc + n] + v;
                    C[(ll)m * ldc + n] = nv;
                    Cb[(ll)m * ldcb + n] = f2bf(nv);
                }
            }
}

// ---------------- causal dwconv(4) + bias + silu, ushort4-vectorized ----------------
__global__ __launch_bounds__(256) void conv_k(const u16* __restrict__ xzb,
                                              const float* __restrict__ cw,
                                              const float* __restrict__ cb,
                                              float* __restrict__ xc,
                                              u16* __restrict__ xcb) {
    int row = blockIdx.x;  // b*1024+t
    int b = row >> 10, t = row & 1023;
    int c0 = threadIdx.x << 2;
    float4 a = *(const float4*)&cb[c0];
    float acc[4] = {a.x, a.y, a.z, a.w};
    float4 cwv[4];
#pragma unroll
    for (int e = 0; e < 4; e++) cwv[e] = *(const float4*)&cw[(c0 + e) << 2];
#pragma unroll
    for (int j = 0; j < 4; j++) {
        int tt = t - 3 + j;
        if (tt >= 0) {
            ushort4 v = *(const ushort4*)&xzb[((ll)(b * T_SZ + tt)) * (2 * DI) + c0];
            acc[0] = fmaf(bf2f(v.x), ((const float*)&cwv[0])[j], acc[0]);
            acc[1] = fmaf(bf2f(v.y), ((const float*)&cwv[1])[j], acc[1]);
            acc[2] = fmaf(bf2f(v.z), ((const float*)&cwv[2])[j], acc[2]);
            acc[3] = fmaf(bf2f(v.w), ((const float*)&cwv[3])[j], acc[3]);
        }
    }
    float4 s; ushort4 sb;
    s.x = siluf(acc[0]); s.y = siluf(acc[1]); s.z = siluf(acc[2]); s.w = siluf(acc[3]);
    sb.x = f2bf(s.x); sb.y = f2bf(s.y); sb.z = f2bf(s.z); sb.w = f2bf(s.w);
    *(float4*)&xc[(ll)row * DI + c0] = s;
    *(ushort4*)&xcb[(ll)row * DI + c0] = sb;
}

// ---------------- chunked selective scan ----------------
// pass 1: per-chunk (prodA, U). grid = B*NCHUNK*(DI/256) = 512 blocks
__global__ __launch_bounds__(256) void scan1_k(const float* __restrict__ dt,
                                               const float* __restrict__ xc,
                                               const float* __restrict__ xdbl,
                                               const float* __restrict__ A_log,
                                               float* __restrict__ pA, float* __restrict__ U) {
    int blk = blockIdx.x;
    int dblk = blk & 3;
    int c = (blk >> 2) & (NCHUNK - 1);
    int b = blk >> 8;
    int d = dblk * 256 + threadIdx.x;
    int t0 = c * TCHUNK;
    __shared__ float BC[TCHUNK][32];
    if (threadIdx.x < TCHUNK * 8) {
        int rr = threadIdx.x >> 3, cc = (threadIdx.x & 7) << 2;
        *(float4*)&BC[rr][cc] = *(const float4*)&xdbl[((ll)(b * T_SZ + t0 + rr)) * 64 + DTR + cc];
    }
    float Av[NS];
#pragma unroll
    for (int n4 = 0; n4 < 4; n4++) {
        float4 alv = *(const float4*)&A_log[d * NS + (n4 << 2)];
        Av[(n4 << 2) + 0] = -__expf(alv.x); Av[(n4 << 2) + 1] = -__expf(alv.y);
        Av[(n4 << 2) + 2] = -__expf(alv.z); Av[(n4 << 2) + 3] = -__expf(alv.w);
    }
    __syncthreads();
    float p[NS], u[NS];
#pragma unroll
    for (int n = 0; n < NS; n++) { p[n] = 1.f; u[n] = 0.f; }
#pragma unroll
    for (int s = 0; s < TCHUNK; s++) {
        ll ro = (ll)(b * T_SZ + t0 + s);
        float dtv = dt[ro * DI + d];
        float xv = xc[ro * DI + d];
        float dx = dtv * xv;
#pragma unroll
        for (int n = 0; n < NS; n++) {
            float aa = __expf(dtv * Av[n]);
            p[n] *= aa;
            u[n] = fmaf(aa, u[n], dx * BC[s][n]);
        }
    }
    ll o = (((ll)b * NCHUNK + c) * DI + d) * NS;
#pragma unroll
    for (int n = 0; n < NS; n++) { pA[o + n] = p[n]; U[o + n] = u[n]; }
}

// pass 2: combine over chunks; hst aliases U (read U before write)
__global__ __launch_bounds__(256) void scan2_k(const float* __restrict__ pA,
                                               const float* __restrict__ U,
                                               float* __restrict__ hst) {
    int i = blockIdx.x * 256 + threadIdx.x;  // b*(DI*NS) + d*NS + n
    int b = i >> 14;
    int rest = i & 16383;
    float h = 0.f;
#pragma unroll
    for (int c = 0; c < NCHUNK; c++) {
        ll o = ((ll)b * NCHUNK + c) * (DI * NS) + rest;
        float pa = pA[o], u = U[o];
        hst[o] = h;
        h = fmaf(pa, h, u);
    }
}

// pass 3: replay with true initial h; fuse D_skip + silu(z) gate; bf16 y out
__global__ __launch_bounds__(256) void scan3_k(const float* __restrict__ dt,
                                               const float* __restrict__ xc,
                                               const float* __restrict__ xdbl,
                                               const u16* __restrict__ xzb,
                                               const float* __restrict__ A_log,
                                               const float* __restrict__ Dk,
                                               const float* __restrict__ hst,
                                               u16* __restrict__ y) {
    int blk = blockIdx.x;
    int dblk = blk & 3;
    int c = (blk >> 2) & (NCHUNK - 1);
    int b = blk >> 8;
    int d = dblk * 256 + threadIdx.x;
    int t0 = c * TCHUNK;
    __shared__ float BC[TCHUNK][32];
    if (threadIdx.x < TCHUNK * 8) {
        int rr = threadIdx.x >> 3, cc = (threadIdx.x & 7) << 2;
        *(float4*)&BC[rr][cc] = *(const float4*)&xdbl[((ll)(b * T_SZ + t0 + rr)) * 64 + DTR + cc];
    }
    float Av[NS];
#pragma unroll
    for (int n4 = 0; n4 < 4; n4++) {
        float4 alv = *(const float4*)&A_log[d * NS + (n4 << 2)];
        Av[(n4 << 2) + 0] = -__expf(alv.x); Av[(n4 << 2) + 1] = -__expf(alv.y);
        Av[(n4 << 2) + 2] = -__expf(alv.z); Av[(n4 << 2) + 3] = -__expf(alv.w);
    }
    float h[NS];
    ll ho = (((ll)b * NCHUNK + c) * DI + d) * NS;
#pragma unroll
    for (int n = 0; n < NS; n++) h[n] = hst[ho + n];
    float Dv = Dk[d];
    __syncthreads();
#pragma unroll
    for (int s = 0; s < TCHUNK; s++) {
        ll ro = (ll)(b * T_SZ + t0 + s);
        float dtv = dt[ro * DI + d];
        float xv = xc[ro * DI + d];
        float dx = dtv * xv;
        float acc = 0.f;
#pragma unroll
        for (int n = 0; n < NS; n++) {
            float aa = __expf(dtv * Av[n]);
            h[n] = fmaf(aa, h[n], dx * BC[s][n]);
            acc = fmaf(h[n], BC[s][16 + n], acc);
        }
        float zv = bf2f(xzb[ro * (2 * DI) + DI + d]);
        y[ro * DI + d] = f2bf((acc + xv * Dv) * siluf(zv));
    }
}

extern "C" void kernel_launch(void* const* d_in, const int* in_sizes, int n_in,
                              void* d_out, int out_size, void* d_ws, size_t ws_size,
                              hipStream_t stream) {
    const int*   codes   = (const int*)d_in[0];
    const float* embed_w = (const float*)d_in[1];
    const float* norm_w  = (const float*)d_in[2];
    const float* in_w    = (const float*)d_in[3];
    const float* conv_w  = (const float*)d_in[4];
    const float* conv_b  = (const float*)d_in[5];
    const float* xp_w    = (const float*)d_in[6];
    const float* dtp_w   = (const float*)d_in[7];
    const float* dtp_b   = (const float*)d_in[8];
    const float* A_log   = (const float*)d_in[9];
    const float* D_skip  = (const float*)d_in[10];
    const float* out_w   = (const float*)d_in[11];
    const float* head_w  = (const float*)d_in[12];
    float* out = (float*)d_out;

    float* ws = (float*)d_ws;
    float* x    = ws;                  // 1,048,576 f32
    float* xc   = x + 1048576;         // 2,097,152
    float* dtb  = xc + 2097152;        // 2,097,152
    float* xdbl = dtb + 2097152;       // 131,072
    float* pA   = xdbl + 131072;       // 2,097,152
    float* Uh   = pA + 2097152;        // 2,097,152 (U, then hst in-place)

    u16* us       = (u16*)(Uh + 2097152);
    u16* xz_bf    = us;                 // 4,194,304
    u16* xc_bf    = xz_bf + 4194304;    // 2,097,152 (x_bf shares first 1M, disjoint lifetime)
    u16* ybxn_bf  = xc_bf + 2097152;    // 2,097,152 (y_bf full; xn_bf shares first 1M)
    u16* xdbl_bf  = ybxn_bf + 2097152;  // 131,072
    u16* w_in_bf  = xdbl_bf + 131072;   // 2,097,152
    u16* w_xp_bf  = w_in_bf + 2097152;  // 131,072
    u16* w_dt_bf  = w_xp_bf + 131072;   // 65,536
    u16* w_out_bf = w_dt_bf + 65536;    // 1,048,576
    u16* w_hd_bf  = w_out_bf + 1048576; // 2,097,152 ([4096][512])

    u16* xn_bf = ybxn_bf;
    u16* y_bf  = ybxn_bf;
    u16* x_bf  = xc_bf;

    // setup: weight conversions + head transpose + embed/rmsnorm, one dispatch
    mega0_k<<<5824, 256, 0, stream>>>(in_w, xp_w, dtp_w, out_w,
                                      w_in_bf, w_xp_bf, w_dt_bf, w_out_bf,
                                      head_w, w_hd_bf, codes, embed_w, norm_w, x, xn_bf);

    for (int l = 0; l < 2; l++) {
        const float* al = A_log + l * DI * NS;
        if (l == 1)
            rmsnorm_k<<<2048, 256, 0, stream>>>(x, norm_w + DM, xn_bf);
        // xz = xn @ in_w^T : (2048 x 2048), K=512 -> bf16.  128x128 tiles, 256 blocks
        mgemm2_k<0><<<dim3(16, 16), 256, 0, stream>>>(xn_bf, DM, w_in_bf + l * 1048576,
                                                      nullptr, xz_bf, 2 * DI, DM);
        conv_k<<<2048, 256, 0, stream>>>(xz_bf, conv_w + l * DI * 4, conv_b + l * DI, xc, xc_bf);
        // x_dbl = xc @ xp_w^T : (2048 x 64), K=1024 -> f32 + bf16
        mgemm_k<1><<<dim3(1, 32), 256, 0, stream>>>(xc_bf, DI, w_xp_bf + l * 65536,
                                                    xdbl, 64, DI, nullptr, xdbl_bf, 64);
        // dt = softplus(x_dbl[:, :32] @ dtp_w^T + b) : (2048 x 1024), K=32
        mgemm_k<2><<<dim3(16, 32), 256, 0, stream>>>(xdbl_bf, 64, w_dt_bf + l * 32768,
                                                     dtb, DI, DTR, dtp_b + l * DI, nullptr, 0);
        scan1_k<<<512, 256, 0, stream>>>(dtb, xc, xdbl, al, pA, Uh);
        scan2_k<<<128, 256, 0, stream>>>(pA, Uh, Uh);
        scan3_k<<<512, 256, 0, stream>>>(dtb, xc, xdbl, xz_bf, al, D_skip + l * DI, Uh, y_bf);
        // x += y @ out_w^T : (2048 x 512), K=1024; also x_bf = bf16(x)
        mgemm_k<3><<<dim3(8, 32), 256, 0, stream>>>(y_bf, DI, w_out_bf + l * 524288,
                                                    x, DM, DI, nullptr, x_bf, DM);
    }

    // head: single GEMM M=2048 x N=4096 x K=512, 128x128 tiles, 512 blocks = 2 blk/CU
    mgemm2_k<4><<<dim3(32, 16), 256, 0, stream>>>(x_bf, DM, w_hd_bf, out, nullptr, 0, DM);
}